// Round 1
// baseline (100.892 us; speedup 1.0000x reference)
//
#include <hip/hip_runtime.h>

#define W_OUT 3840
#define H_OUT 2160
#define IW 1024   // intermediate (cropped) cols
#define IH 576    // intermediate (cropped) rows

__device__ __forceinline__ unsigned int enc_f32(float f) {
    // order-preserving float->uint map (for min over all reals)
    unsigned int b = __float_as_uint(f);
    return (b & 0x80000000u) ? ~b : (b | 0x80000000u);
}

// Kernel 1: sim64[p] = sum_c ref[c]*emb[c][p] / sqrt(sum_c emb[c][p]^2)
// 64 blocks x 256 threads; wave w handles channel chunk [64w,64w+64), lane = position
__global__ __launch_bounds__(256) void sim_kernel(
    const float* __restrict__ emb, const float* __restrict__ ref,
    float* __restrict__ sim, unsigned long long* __restrict__ cells,
    unsigned long long* __restrict__ bg)
{
    const int lane = threadIdx.x & 63;
    const int wave = threadIdx.x >> 6;
    const int p = blockIdx.x * 64 + lane;
    const int cbase = wave * 64;
    float dot = 0.f, ss = 0.f;
#pragma unroll 8
    for (int cc = 0; cc < 64; ++cc) {
        int c = cbase + cc;
        float a = emb[c * 4096 + p];
        dot = fmaf(ref[c], a, dot);
        ss  = fmaf(a, a, ss);
    }
    __shared__ float sdot[4][64];
    __shared__ float sss[4][64];
    sdot[wave][lane] = dot;
    sss[wave][lane]  = ss;
    __syncthreads();
    if (wave == 0) {
        float d = (sdot[0][lane] + sdot[1][lane]) + (sdot[2][lane] + sdot[3][lane]);
        float s = (sss[0][lane] + sss[1][lane]) + (sss[2][lane] + sss[3][lane]);
        sim[p] = d / sqrtf(s);
    }
    // init reduction slots (ws is poisoned 0xAA before every launch)
    if (blockIdx.x == 0) {
        cells[threadIdx.x] = 0ull;
        if (threadIdx.x == 0) *bg = 0xFFFFFFFFFFFFFFFFull;
    }
}

// Kernel 2: one block per output row y (2160 blocks x 256 threads).
// Build the two needed intermediate rows (576x1024 cropped 16x-upsample of sim64)
// in LDS, then scan 3840 pixels: global argmin + per-cell thresholded argmax.
__global__ __launch_bounds__(256) void scan_kernel(
    const float* __restrict__ sim,
    unsigned long long* __restrict__ cells,
    unsigned long long* __restrict__ bg)
{
    __shared__ float ldsI[2][IW];
    __shared__ unsigned long long red[256];

    const float INV375 = (float)(1.0 / 3.75);            // jax inv_scale, f32
    const float INV16  = 0.0625f;
    const float CELL_R = (float)(1024.0 / 3840.0 / 64.0); // ratio/DOWNSIZING, f32

    const int y   = blockIdx.x;
    const int tid = threadIdx.x;

    // second-stage row weights (uniform over block)
    float fy  = ((float)y + 0.5f) * INV375 - 0.5f;
    float fyf = floorf(fy);
    float wy  = fy - fyf;
    int ai = (int)fyf;
    int a1 = min(max(ai + 1, 0), IH - 1);
    int a0 = min(max(ai,     0), IH - 1);

    // fill intermediate rows a0, a1 (first-stage bilinear from sim64)
    for (int r = 0; r < 2; ++r) {
        int a = (r == 0) ? a0 : a1;
        float fa  = ((float)a + 0.5f) * INV16 - 0.5f;
        float faf = floorf(fa);
        float wa  = fa - faf;
        int si = (int)faf;
        int s1 = min(max(si + 1, 0), 63);
        int s0 = min(max(si,     0), 63);
        const float* row0 = sim + s0 * 64;
        const float* row1 = sim + s1 * 64;
        for (int b = tid; b < IW; b += 256) {
            float fb  = ((float)b + 0.5f) * INV16 - 0.5f;
            float fbf = floorf(fb);
            float wb  = fb - fbf;
            int ci = (int)fbf;
            int c1 = min(max(ci + 1, 0), 63);
            int c0 = min(max(ci,     0), 63);
            float v0 = row0[c0] * (1.f - wb) + row0[c1] * wb;
            float v1 = row1[c0] * (1.f - wb) + row1[c1] * wb;
            ldsI[r][b] = v0 * (1.f - wa) + v1 * wa;
        }
    }
    __syncthreads();

    unsigned long long best = 0xFFFFFFFFFFFFFFFFull;
#pragma unroll
    for (int k = 0; k < 15; ++k) {
        int x = k * 256 + tid;
        float fx  = ((float)x + 0.5f) * INV375 - 0.5f;
        float fxf = floorf(fx);
        float wx  = fx - fxf;
        int bi = (int)fxf;
        int b1 = min(max(bi + 1, 0), IW - 1);
        int b0 = min(max(bi,     0), IW - 1);
        float v0 = ldsI[0][b0] * (1.f - wx) + ldsI[0][b1] * wx;
        float v1 = ldsI[1][b0] * (1.f - wx) + ldsI[1][b1] * wx;
        float F  = v0 * (1.f - wy) + v1 * wy;

        unsigned int idx = (unsigned int)(y * W_OUT + x);
        unsigned long long key = ((unsigned long long)enc_f32(F) << 32) | (unsigned long long)idx;
        if (key < best) best = key;

        if (F > 0.65f) {  // rare path: positive floats -> bit-monotone
            int gx = (int)floorf((float)x * CELL_R);
            int gy = (int)floorf((float)y * CELL_R);
            int seg = gy * 16 + gx;
            unsigned long long ck =
                ((unsigned long long)__float_as_uint(F) << 32) |
                (unsigned long long)(0xFFFFFFFFu - idx);
            atomicMax(&cells[seg], ck);
        }
    }

    red[tid] = best;
    __syncthreads();
    for (int s = 128; s > 0; s >>= 1) {
        if (tid < s) {
            unsigned long long o = red[tid + s];
            if (o < red[tid]) red[tid] = o;
        }
        __syncthreads();
    }
    if (tid == 0) atomicMin(bg, red[0]);
}

// Kernel 3: decode 256 cells, stable rank-sort by score desc, write output.
__global__ __launch_bounds__(256) void finalize_kernel(
    const unsigned long long* __restrict__ cells,
    const unsigned long long* __restrict__ bg,
    float* __restrict__ out)
{
    __shared__ float sk[256];
    const int t = threadIdx.x;
    unsigned long long ck = cells[t];
    float px = -1.f, py = -1.f, ps = -1.f;
    float key = -__builtin_huge_valf();
    if (ck != 0ull) {
        unsigned int bits = (unsigned int)(ck >> 32);
        unsigned int idx  = 0xFFFFFFFFu - (unsigned int)(ck & 0xFFFFFFFFull);
        float v = __uint_as_float(bits);
        px = (float)(idx % W_OUT);
        py = (float)(idx / W_OUT);
        ps = v;
        key = v;
    }
    sk[t] = key;
    __syncthreads();
    int rank = 0;
    for (int j = 0; j < 256; ++j) {
        float kj = sk[j];
        if (kj > key || (kj == key && j < t)) rank++;
    }
    out[rank * 3 + 0] = px;
    out[rank * 3 + 1] = py;
    out[rank * 3 + 2] = ps;
    if (t == 0) {
        unsigned long long b = *bg;
        unsigned int idx = (unsigned int)(b & 0xFFFFFFFFull);
        out[256 * 3 + 0] = (float)(idx % W_OUT);  // bg col (x)
        out[256 * 3 + 1] = (float)(idx / W_OUT);  // bg row (y)
    }
}

extern "C" void kernel_launch(void* const* d_in, const int* in_sizes, int n_in,
                              void* d_out, int out_size, void* d_ws, size_t ws_size,
                              hipStream_t stream) {
    (void)in_sizes; (void)n_in; (void)out_size; (void)ws_size;
    const float* emb = (const float*)d_in[0];   // (1,256,64,64) f32
    const float* ref = (const float*)d_in[1];   // (1,256) f32
    // d_in[2] = ori_shape (2160,3840) -- baked as constants, matching reference trace
    float* out = (float*)d_out;                 // 256*3 points + 2 bg coords

    float* sim = (float*)d_ws;                                              // 4096 f32
    unsigned long long* cells = (unsigned long long*)((char*)d_ws + 4096*4); // 256 u64
    unsigned long long* bg    = cells + 256;                                 // 1 u64

    sim_kernel<<<64, 256, 0, stream>>>(emb, ref, sim, cells, bg);
    scan_kernel<<<H_OUT, 256, 0, stream>>>(sim, cells, bg);
    finalize_kernel<<<1, 256, 0, stream>>>(cells, bg, out);
}